// Round 1
// 585.910 us; speedup vs baseline: 1.0864x; 1.0864x over previous
//
#include <hip/hip_runtime.h>
#include <hip/hip_bf16.h>
#include <math.h>

#define T_   32
#define C_   128
#define GD_  64
#define KQK_ 192
#define NH_  4
#define HD_  32
#define C4_  512
#define HW_  1024

typedef unsigned short u16;
typedef __attribute__((ext_vector_type(8))) short short8;
typedef __attribute__((ext_vector_type(4))) float f32x4;
typedef __attribute__((ext_vector_type(4))) unsigned short u16x4;

// ---- ws layout (u16 element offsets) ----
#define WQH 0
#define WQL 24576
#define WKH 49152
#define WKL 73728
#define WVH 98304
#define WVL 114688
#define W1H 131072
#define W1L 196608
#define W2H 262144
#define W2L 327680
#define GSH 393216
#define GSL 401408
#define XT  409600           // per-n interleaved: [n][hi 4096 u16 | lo 4096 u16]
#define WS_NEED_BYTES (819200ull + 4096ull*8192ull*2ull)   // 67,928,064

// ---- LDS pool byte offsets (K^T/V^T/KV^T/Q now register-resident) ----
#define AX_H  0        // [32][200] u16 (x|g hi), stride 400 B
#define AX_L  12800    // [32][200] u16 (lo), ends 25600
#define O1B   0        // [32][132] f32 overlays AX after phase D barrier (16896 B)
#define X2A_H 16896    // rows 0-15 of x2 hi [16][136] u16
#define X2A_L 21248    // rows 0-15 lo, ends 25600
#define HM_H  25600    // [32][136] u16
#define HM_L  34304    // ends 43008
#define X2B_H 43008    // rows 16-31 hi
#define X2B_L 47360    // ends 51712
#define STATS 51712    // 128 f32: mu1[32] rstd1[32] mu2[32] rstd2[32]
#define KSUM  52224    // 128 f32
#define ZDEN  52736    // 128 f32
#define POOLB 53248    // 3 blocks/CU (<= 163840/3)

__device__ __forceinline__ float b2f(u16 u) {
    unsigned int x = ((unsigned int)u) << 16;
    float f; __builtin_memcpy(&f, &x, 4); return f;
}
__device__ __forceinline__ u16 f2b(float f) {
    __hip_bfloat16 h = __float2bfloat16(f);
    u16 u; __builtin_memcpy(&u, &h, 2); return u;
}
__device__ __forceinline__ void split2(float v, u16& h, u16& l) {
    h = f2b(v); l = f2b(v - b2f(h));
}
__device__ __forceinline__ unsigned int pack2(u16 a, u16 b) {
    return (unsigned int)a | ((unsigned int)b << 16);
}

// Quad-group transpose: source acc tiles P0 (dim<16) / P1 (dim>=16) hold the
// transposed dimension as (quad*4+r); target fragment wants it as k=(quad*8+i).
// p?0 = pack(r0,r1), p?1 = pack(r2,r3). Returns a short8 MFMA operand fragment.
__device__ __forceinline__ short8 qtrans(unsigned int p00, unsigned int p01,
                                         unsigned int p10, unsigned int p11, int lane)
{
    int sA = (lane & 15) + ((lane & 16) << 1);   // l16 + 32*(quad&1)
    int sB = sA + 16;
    unsigned int a0 = __shfl((int)p00, sA), b0 = __shfl((int)p10, sA);
    unsigned int a1 = __shfl((int)p01, sA), b1 = __shfl((int)p11, sA);
    unsigned int a2 = __shfl((int)p00, sB), b2 = __shfl((int)p10, sB);
    unsigned int a3 = __shfl((int)p01, sB), b3 = __shfl((int)p11, sB);
    bool hi = (lane & 32) != 0;                  // quad >= 2 -> source tile 1
    union { unsigned int u[4]; short8 s; } c;
    c.u[0] = hi ? b0 : a0;
    c.u[1] = hi ? b1 : a1;
    c.u[2] = hi ? b2 : a2;
    c.u[3] = hi ? b3 : a3;
    return c.s;
}

#define MFMA3(acc, ah, al, bh, bl)                                          \
    acc = __builtin_amdgcn_mfma_f32_16x16x32_bf16(ah, bh, acc, 0, 0, 0);    \
    acc = __builtin_amdgcn_mfma_f32_16x16x32_bf16(ah, bl, acc, 0, 0, 0);    \
    acc = __builtin_amdgcn_mfma_f32_16x16x32_bf16(al, bh, acc, 0, 0, 0);

// ---- prep: split weights (transposed [n][K]) + guidance to bf16 hi/lo ----
__global__ void prep_weights(const float* __restrict__ Wq, const float* __restrict__ Wk,
                             const float* __restrict__ Wv, const float* __restrict__ W1,
                             const float* __restrict__ W2, const float* __restrict__ gui,
                             u16* __restrict__ wsp)
{
    int e = blockIdx.x * 256 + threadIdx.x;
    if (e >= 196608) {                       // guidance tail: 8192 elems
        int idx = e - 196608;
        float v = gui[idx];
        u16 hb = f2b(v);
        wsp[GSH + idx] = hb;
        wsp[GSL + idx] = f2b(v - b2f(hb));
        return;
    }
    const float* src; int e2, k, n, K; int oh, ol;
    if (e < 24576)       { src = Wq; e2 = e;          k = e2 >> 7; n = e2 & 127; K = KQK_; oh = WQH; ol = WQL; }
    else if (e < 49152)  { src = Wk; e2 = e - 24576;  k = e2 >> 7; n = e2 & 127; K = KQK_; oh = WKH; ol = WKL; }
    else if (e < 65536)  { src = Wv; e2 = e - 49152;  k = e2 >> 7; n = e2 & 127; K = C_;   oh = WVH; ol = WVL; }
    else if (e < 131072) { src = W1; e2 = e - 65536;  k = e2 >> 9; n = e2 & 511; K = C_;   oh = W1H; ol = W1L; }
    else                 { src = W2; e2 = e - 131072; k = e2 >> 7; n = e2 & 127; K = C4_;  oh = W2H; ol = W2L; }
    float w = src[e2];
    u16 hb = f2b(w);
    wsp[oh + n * K + k] = hb;
    wsp[ol + n * K + k] = f2b(w - b2f(hb));
}

// ---- transpose x (B,T,C,H,W) -> xT[n][t][c] split bf16 planes (coalesced both sides) ----
__global__ __launch_bounds__(256) void transpose_x(const float* __restrict__ x, u16* __restrict__ wsp)
{
    __shared__ float tile[32][65];
    int bid = blockIdx.x;
    int hq = bid & 15, cq = (bid >> 4) & 3, t = (bid >> 6) & 31, b = bid >> 11;
    int c0 = cq * 32, hw0 = hq * 64;
    int tid = threadIdx.x;
    {
        int i = tid >> 3, j8 = (tid & 7) * 8;
        const float* src = x + ((size_t)((b*32 + t)*128 + c0 + i))*1024 + hw0 + j8;
        float4 v0 = *reinterpret_cast<const float4*>(src);
        float4 v1 = *reinterpret_cast<const float4*>(src + 4);
        tile[i][j8+0]=v0.x; tile[i][j8+1]=v0.y; tile[i][j8+2]=v0.z; tile[i][j8+3]=v0.w;
        tile[i][j8+4]=v1.x; tile[i][j8+5]=v1.y; tile[i][j8+6]=v1.z; tile[i][j8+7]=v1.w;
    }
    __syncthreads();
    {
        int jj = tid >> 2, c8 = (tid & 3) * 8;
        int n = b*1024 + hw0 + jj;
        ushort4 h0, h1, l0, l1;
        u16 hh[8], ll[8];
        #pragma unroll
        for (int ii = 0; ii < 8; ++ii) {
            float v = tile[c8 + ii][jj];
            u16 hb = f2b(v);
            hh[ii] = hb; ll[ii] = f2b(v - b2f(hb));
        }
        h0 = make_ushort4(hh[0],hh[1],hh[2],hh[3]); h1 = make_ushort4(hh[4],hh[5],hh[6],hh[7]);
        l0 = make_ushort4(ll[0],ll[1],ll[2],ll[3]); l1 = make_ushort4(ll[4],ll[5],ll[6],ll[7]);
        u16* dh = wsp + XT + (size_t)n*8192 + t*128 + c0 + c8;
        u16* dl = dh + 4096;
        *reinterpret_cast<ushort4*>(dh)     = h0;
        *reinterpret_cast<ushort4*>(dh + 4) = h1;
        *reinterpret_cast<ushort4*>(dl)     = l0;
        *reinterpret_cast<ushort4*>(dl + 4) = l1;
    }
}

__global__ __launch_bounds__(256, 3) void fused_linattn_mfma(
    const float* __restrict__ x,
    const float* __restrict__ bq, const float* __restrict__ bk, const float* __restrict__ bv,
    const float* __restrict__ g1, const float* __restrict__ be1,
    const float* __restrict__ g2, const float* __restrict__ be2,
    const float* __restrict__ b1, const float* __restrict__ b2,
    const u16* __restrict__ wsp, int use_xt,
    float* __restrict__ out)
{
    extern __shared__ __align__(16) char pool[];
    float* ksum  = (float*)(pool + KSUM);
    float* stats = (float*)(pool + STATS);
    float* zden  = (float*)(pool + ZDEN);

    const int bi  = blockIdx.x;
    const int n_  = ((bi & 7) << 9) | (bi >> 3);
    const int b   = n_ >> 10;
    const int hw  = n_ & 1023;
    const int tid = threadIdx.x;
    const int lane = tid & 63, wv = tid >> 6;
    const int l16  = lane & 15, quad = lane >> 4;

    // ---- Phase A: stage x|g split planes into AX ----
    if (use_xt) {
        const u16* xtb = wsp + XT + (size_t)n_ * 8192;
        #pragma unroll
        for (int i = 0; i < 2; ++i) {
            int off = (tid + i*256) * 8;            // element idx (t*128+c), 8 contiguous
            int t = off >> 7, c = off & 127;
            short8 vh = *reinterpret_cast<const short8*>(xtb + off);
            short8 vl = *reinterpret_cast<const short8*>(xtb + 4096 + off);
            *reinterpret_cast<short8*>(pool + AX_H + t*400 + c*2) = vh;
            *reinterpret_cast<short8*>(pool + AX_L + t*400 + c*2) = vl;
        }
    } else {
        const float* xb = x + (size_t)b * (T_*C_*HW_) + hw;
        #pragma unroll
        for (int i = 0; i < 16; ++i) {
            int idx = tid + i*256;
            float v = xb[(size_t)idx * HW_];
            int t = idx >> 7, c = idx & 127;
            u16 hb = f2b(v);
            *(u16*)(pool + AX_H + t*400 + c*2) = hb;
            *(u16*)(pool + AX_L + t*400 + c*2) = f2b(v - b2f(hb));
        }
    }
    {
        const u16* gh = wsp + GSH + b*2048 + tid*8;
        const u16* gl = wsp + GSL + b*2048 + tid*8;
        int off = tid * 8;                          // t*64 + jg
        int t = off >> 6, jg = off & 63;
        short8 vh = *reinterpret_cast<const short8*>(gh);
        short8 vl = *reinterpret_cast<const short8*>(gl);
        *reinterpret_cast<short8*>(pool + AX_H + t*400 + 256 + jg*2) = vh;
        *reinterpret_cast<short8*>(pool + AX_L + t*400 + 256 + jg*2) = vl;
    }
    __syncthreads();

    // ---- Phase B: QKV projections; Q/K/V fragments stay in registers ----
    // wave wv owns channels [wv*32, wv*32+32) == head wv exactly.
    short8 qfh[2], qfl[2];   // Q B-frags: [token tile], k = head-local d
    short8 kfh[2], kfl[2];   // K^T A-frags: [d tile], k = token
    short8 vfh[2], vfl[2];   // V^T B-frags: [v tile], k = token
    {
        // ---------------- Q (swapped operands: acc = [channel][token]) ----------------
        f32x4 acc[2][2];
        #pragma unroll
        for (int mt = 0; mt < 2; ++mt)
            #pragma unroll
            for (int nt = 0; nt < 2; ++nt) acc[mt][nt] = (f32x4){0.f,0.f,0.f,0.f};
        #pragma unroll
        for (int ks = 0; ks < 6; ++ks) {
            short8 ah[2], al[2];
            #pragma unroll
            for (int mt = 0; mt < 2; ++mt) {
                ah[mt] = *(const short8*)(pool + AX_H + (mt*16 + l16)*400 + ks*64 + quad*16);
                al[mt] = *(const short8*)(pool + AX_L + (mt*16 + l16)*400 + ks*64 + quad*16);
            }
            #pragma unroll
            for (int nt = 0; nt < 2; ++nt) {
                int n = (wv*2 + nt)*16 + l16;
                short8 bh = *(const short8*)(wsp + WQH + n*KQK_ + ks*32 + quad*8);
                short8 bl = *(const short8*)(wsp + WQL + n*KQK_ + ks*32 + quad*8);
                #pragma unroll
                for (int mt = 0; mt < 2; ++mt) { MFMA3(acc[mt][nt], bh, bl, ah[mt], al[mt]); }
            }
        }
        #pragma unroll
        for (int mt = 0; mt < 2; ++mt) {
            unsigned int ph[2][2], pl[2][2];
            #pragma unroll
            for (int nt = 0; nt < 2; ++nt) {
                f32x4 b4 = *(const f32x4*)(bq + wv*32 + nt*16 + quad*4);
                u16 hh[4], ll[4];
                #pragma unroll
                for (int r = 0; r < 4; ++r) {
                    float q = acc[mt][nt][r] + b4[r];
                    float qp = (q > 0.f) ? q + 1.f : __expf(q);
                    split2(qp, hh[r], ll[r]);
                }
                ph[nt][0] = pack2(hh[0],hh[1]); ph[nt][1] = pack2(hh[2],hh[3]);
                pl[nt][0] = pack2(ll[0],ll[1]); pl[nt][1] = pack2(ll[2],ll[3]);
            }
            qfh[mt] = qtrans(ph[0][0], ph[0][1], ph[1][0], ph[1][1], lane);
            qfl[mt] = qtrans(pl[0][0], pl[0][1], pl[1][0], pl[1][1], lane);
        }
        // ---------------- K (orig orientation: acc = [token][channel]) + ksum ----------------
        #pragma unroll
        for (int mt = 0; mt < 2; ++mt)
            #pragma unroll
            for (int nt = 0; nt < 2; ++nt) acc[mt][nt] = (f32x4){0.f,0.f,0.f,0.f};
        #pragma unroll
        for (int ks = 0; ks < 6; ++ks) {
            short8 ah[2], al[2];
            #pragma unroll
            for (int mt = 0; mt < 2; ++mt) {
                ah[mt] = *(const short8*)(pool + AX_H + (mt*16 + l16)*400 + ks*64 + quad*16);
                al[mt] = *(const short8*)(pool + AX_L + (mt*16 + l16)*400 + ks*64 + quad*16);
            }
            #pragma unroll
            for (int nt = 0; nt < 2; ++nt) {
                int n = (wv*2 + nt)*16 + l16;
                short8 bh = *(const short8*)(wsp + WKH + n*KQK_ + ks*32 + quad*8);
                short8 bl = *(const short8*)(wsp + WKL + n*KQK_ + ks*32 + quad*8);
                #pragma unroll
                for (int mt = 0; mt < 2; ++mt) { MFMA3(acc[mt][nt], ah[mt], al[mt], bh, bl); }
            }
        }
        float sk0 = 0.f, sk1 = 0.f;
        #pragma unroll
        for (int nt = 0; nt < 2; ++nt) {
            float bias = bk[wv*32 + nt*16 + l16];
            unsigned int ph[2][2], pl[2][2];
            #pragma unroll
            for (int mt = 0; mt < 2; ++mt) {
                u16 hh[4], ll[4];
                #pragma unroll
                for (int r = 0; r < 4; ++r) {
                    float k = acc[mt][nt][r] + bias;
                    float kp = (k > 0.f) ? k + 1.f : __expf(k);
                    if (nt == 0) sk0 += kp; else sk1 += kp;
                    split2(kp, hh[r], ll[r]);
                }
                ph[mt][0] = pack2(hh[0],hh[1]); ph[mt][1] = pack2(hh[2],hh[3]);
                pl[mt][0] = pack2(ll[0],ll[1]); pl[mt][1] = pack2(ll[2],ll[3]);
            }
            kfh[nt] = qtrans(ph[0][0], ph[0][1], ph[1][0], ph[1][1], lane);
            kfl[nt] = qtrans(pl[0][0], pl[0][1], pl[1][0], pl[1][1], lane);
        }
        sk0 += __shfl_xor(sk0, 16); sk0 += __shfl_xor(sk0, 32);
        sk1 += __shfl_xor(sk1, 16); sk1 += __shfl_xor(sk1, 32);
        if (quad == 0) ksum[wv*32 + l16]      = sk0;
        if (quad == 1) ksum[wv*32 + 16 + l16] = sk1;
        // ---------------- V (orig orientation) ----------------
        #pragma unroll
        for (int mt = 0; mt < 2; ++mt)
            #pragma unroll
            for (int nt = 0; nt < 2; ++nt) acc[mt][nt] = (f32x4){0.f,0.f,0.f,0.f};
        #pragma unroll
        for (int ks = 0; ks < 4; ++ks) {
            short8 ah[2], al[2];
            #pragma unroll
            for (int mt = 0; mt < 2; ++mt) {
                ah[mt] = *(const short8*)(pool + AX_H + (mt*16 + l16)*400 + ks*64 + quad*16);
                al[mt] = *(const short8*)(pool + AX_L + (mt*16 + l16)*400 + ks*64 + quad*16);
            }
            #pragma unroll
            for (int nt = 0; nt < 2; ++nt) {
                int n = (wv*2 + nt)*16 + l16;
                short8 bh = *(const short8*)(wsp + WVH + n*C_ + ks*32 + quad*8);
                short8 bl = *(const short8*)(wsp + WVL + n*C_ + ks*32 + quad*8);
                #pragma unroll
                for (int mt = 0; mt < 2; ++mt) { MFMA3(acc[mt][nt], ah[mt], al[mt], bh, bl); }
            }
        }
        #pragma unroll
        for (int nt = 0; nt < 2; ++nt) {
            float bias = bv[wv*32 + nt*16 + l16];
            unsigned int ph[2][2], pl[2][2];
            #pragma unroll
            for (int mt = 0; mt < 2; ++mt) {
                u16 hh[4], ll[4];
                #pragma unroll
                for (int r = 0; r < 4; ++r) {
                    float v = acc[mt][nt][r] + bias;
                    split2(v, hh[r], ll[r]);
                }
                ph[mt][0] = pack2(hh[0],hh[1]); ph[mt][1] = pack2(hh[2],hh[3]);
                pl[mt][0] = pack2(ll[0],ll[1]); pl[mt][1] = pack2(ll[2],ll[3]);
            }
            vfh[nt] = qtrans(ph[0][0], ph[0][1], ph[1][0], ph[1][1], lane);
            vfl[nt] = qtrans(pl[0][0], pl[0][1], pl[1][0], pl[1][1], lane);
        }
    }
    __syncthreads();    // ksum visible; AX stable for stats

    // ---- Phase C: KV in registers; ln1 stats; zden ----
    short8 kvfh[2], kvfl[2];    // KV^T A-frags: [v tile], k = head-local d
    {
        f32x4 kv[2][2];
        #pragma unroll
        for (int dt = 0; dt < 2; ++dt)
            #pragma unroll
            for (int vt = 0; vt < 2; ++vt) {
                kv[dt][vt] = (f32x4){0.f,0.f,0.f,0.f};
                MFMA3(kv[dt][vt], kfh[dt], kfl[dt], vfh[vt], vfl[vt]);
            }
        #pragma unroll
        for (int vt = 0; vt < 2; ++vt) {
            unsigned int ph[2][2], pl[2][2];
            #pragma unroll
            for (int dt = 0; dt < 2; ++dt) {
                u16 hh[4], ll[4];
                #pragma unroll
                for (int r = 0; r < 4; ++r) split2(kv[dt][vt][r], hh[r], ll[r]);
                ph[dt][0] = pack2(hh[0],hh[1]); ph[dt][1] = pack2(hh[2],hh[3]);
                pl[dt][0] = pack2(ll[0],ll[1]); pl[dt][1] = pack2(ll[2],ll[3]);
            }
            kvfh[vt] = qtrans(ph[0][0], ph[0][1], ph[1][0], ph[1][1], lane);
            kvfl[vt] = qtrans(pl[0][0], pl[0][1], pl[1][0], pl[1][1], lane);
        }
    }
    {   // ln1 stats: 8 threads per row t, vectorized reads
        int t = tid >> 3, j = tid & 7;
        const char* rp = pool + AX_H + t*400 + j*32;
        short8 h0 = *(const short8*)(rp);
        short8 h1 = *(const short8*)(rp + 16);
        short8 l0 = *(const short8*)(rp + (AX_L - AX_H));
        short8 l1 = *(const short8*)(rp + (AX_L - AX_H) + 16);
        float m = 0.f, s = 0.f;
        #pragma unroll
        for (int i = 0; i < 8; ++i) {
            float v = b2f((u16)h0[i]) + b2f((u16)l0[i]);
            m += v; s = fmaf(v, v, s);
            v = b2f((u16)h1[i]) + b2f((u16)l1[i]);
            m += v; s = fmaf(v, v, s);
        }
        m += __shfl_xor(m, 1); s += __shfl_xor(s, 1);
        m += __shfl_xor(m, 2); s += __shfl_xor(s, 2);
        m += __shfl_xor(m, 4); s += __shfl_xor(s, 4);
        if (j == 0) {
            float mu = m * (1.f/C_);
            stats[t]      = mu;
            stats[32 + t] = rsqrtf(s * (1.f/C_) - mu*mu + 1e-5f);
        }
    }
    {   // zden from Q-frags: each lane covers d = quad*8..quad*8+7 of head wv
        const float* ksb = ksum + wv*32 + quad*8;
        f32x4 ka = *(const f32x4*)(ksb);
        f32x4 kb = *(const f32x4*)(ksb + 4);
        float p0 = 0.f, p1 = 0.f;
        #pragma unroll
        for (int i = 0; i < 4; ++i) {
            p0 = fmaf(b2f((u16)qfh[0][i])   + b2f((u16)qfl[0][i]),   ka[i], p0);
            p1 = fmaf(b2f((u16)qfh[1][i])   + b2f((u16)qfl[1][i]),   ka[i], p1);
            p0 = fmaf(b2f((u16)qfh[0][4+i]) + b2f((u16)qfl[0][4+i]), kb[i], p0);
            p1 = fmaf(b2f((u16)qfh[1][4+i]) + b2f((u16)qfl[1][4+i]), kb[i], p1);
        }
        p0 += __shfl_xor(p0, 16); p0 += __shfl_xor(p0, 32);
        p1 += __shfl_xor(p1, 16); p1 += __shfl_xor(p1, 32);
        if (quad == 0) zden[l16*NH_ + wv]        = 1.f / (p0 + 1e-6f);
        if (quad == 1) zden[(16 + l16)*NH_ + wv] = 1.f / (p1 + 1e-6f);
    }
    __syncthreads();

    // ---- Phase D: O = KV^T x Q (swapped: acc = [v-channel][token]) + ln1 residual ----
    f32x4 o1v[2][2];
    {
        f32x4 oacc[2][2];
        #pragma unroll
        for (int mt = 0; mt < 2; ++mt)
            #pragma unroll
            for (int nt = 0; nt < 2; ++nt) {
                oacc[mt][nt] = (f32x4){0.f,0.f,0.f,0.f};
                MFMA3(oacc[mt][nt], kvfh[nt], kvfl[nt], qfh[mt], qfl[mt]);
            }
        #pragma unroll
        for (int mt = 0; mt < 2; ++mt) {
            int tk = mt*16 + l16;
            float zd = zden[tk*NH_ + wv];
            float mu = stats[tk], rs = stats[32 + tk];
            #pragma unroll
            for (int nt = 0; nt < 2; ++nt) {
                int ch0 = wv*32 + nt*16 + quad*4;
                f32x4 gg = *(const f32x4*)(g1 + ch0);
                f32x4 bb = *(const f32x4*)(be1 + ch0);
                u16x4 xh = *(const u16x4*)(pool + AX_H + tk*400 + ch0*2);
                u16x4 xl = *(const u16x4*)(pool + AX_L + tk*400 + ch0*2);
                f32x4 o;
                #pragma unroll
                for (int r = 0; r < 4; ++r) {
                    float xv = b2f(xh[r]) + b2f(xl[r]);
                    o[r] = oacc[mt][nt][r]*zd + (xv - mu)*rs*gg[r] + bb[r];
                }
                o1v[mt][nt] = o;
            }
        }
    }
    __syncthreads();    // all AX reads complete before overwrite

    // ---- Phase D2: write o1 f32 over AX (stride 132 f32) ----
    {
        float* O1 = (float*)(pool + O1B);
        #pragma unroll
        for (int mt = 0; mt < 2; ++mt) {
            int tk = mt*16 + l16;
            #pragma unroll
            for (int nt = 0; nt < 2; ++nt) {
                int ch0 = wv*32 + nt*16 + quad*4;
                *(f32x4*)(O1 + tk*132 + ch0) = o1v[mt][nt];
            }
        }
    }
    __syncthreads();

    // ---- Phase E1: ln2 stats ----
    {
        const float* O1 = (const float*)(pool + O1B);
        int t = tid >> 3, j = tid & 7;
        const float* rp = O1 + t*132 + j*16;
        f32x4 a = *(const f32x4*)(rp);
        f32x4 b4 = *(const f32x4*)(rp + 4);
        f32x4 c4 = *(const f32x4*)(rp + 8);
        f32x4 d4 = *(const f32x4*)(rp + 12);
        float m = 0.f, s = 0.f;
        #pragma unroll
        for (int i = 0; i < 4; ++i) {
            m += a[i];  s = fmaf(a[i],  a[i],  s);
            m += b4[i]; s = fmaf(b4[i], b4[i], s);
            m += c4[i]; s = fmaf(c4[i], c4[i], s);
            m += d4[i]; s = fmaf(d4[i], d4[i], s);
        }
        m += __shfl_xor(m, 1); s += __shfl_xor(s, 1);
        m += __shfl_xor(m, 2); s += __shfl_xor(s, 2);
        m += __shfl_xor(m, 4); s += __shfl_xor(s, 4);
        if (j == 0) {
            float mu = m * (1.f/C_);
            stats[64 + t] = mu;
            stats[96 + t] = rsqrtf(s * (1.f/C_) - mu*mu + 1e-5f);
        }
    }
    __syncthreads();

    // ---- Phase E2: x2 = ln2(o1) split planes (split rows 0-15 / 16-31 regions) ----
    {
        const float* O1 = (const float*)(pool + O1B);
        #pragma unroll
        for (int i = 0; i < 4; ++i) {
            int cid = tid + i*256;
            int t = cid >> 5, c0 = (cid & 31)*4;
            f32x4 v = *(const f32x4*)(O1 + t*132 + c0);
            float mu = stats[64 + t], rs = stats[96 + t];
            f32x4 gv = *(const f32x4*)(g2 + c0);
            f32x4 bv2 = *(const f32x4*)(be2 + c0);
            u16 hh[4], ll[4];
            #pragma unroll
            for (int e = 0; e < 4; ++e) {
                float w = (v[e] - mu)*rs*gv[e] + bv2[e];
                split2(w, hh[e], ll[e]);
            }
            char* xb = pool + ((t < 16) ? (X2A_H + t*272) : (X2B_H + (t - 16)*272));
            *(u16x4*)(xb + c0*2)        = (u16x4){hh[0],hh[1],hh[2],hh[3]};
            *(u16x4*)(xb + 4352 + c0*2) = (u16x4){ll[0],ll[1],ll[2],ll[3]};
        }
    }
    __syncthreads();

    // ---- Phases F/G: MLP, 4 chunks of 128 (both GEMMs swapped) ----
    f32x4 accO[2][2];
    #pragma unroll
    for (int mt = 0; mt < 2; ++mt)
        #pragma unroll
        for (int nt = 0; nt < 2; ++nt) accO[mt][nt] = (f32x4){0.f,0.f,0.f,0.f};

    #pragma unroll 1
    for (int mh = 0; mh < 4; ++mh) {
        {
            f32x4 accH[2][2];
            #pragma unroll
            for (int mt = 0; mt < 2; ++mt)
                #pragma unroll
                for (int nt = 0; nt < 2; ++nt) accH[mt][nt] = (f32x4){0.f,0.f,0.f,0.f};
            #pragma unroll
            for (int ks = 0; ks < 4; ++ks) {
                short8 ah[2], al[2];
                #pragma unroll
                for (int mt = 0; mt < 2; ++mt) {
                    const char* xb = pool + (mt ? X2B_H : X2A_H) + l16*272 + ks*64 + quad*16;
                    ah[mt] = *(const short8*)(xb);
                    al[mt] = *(const short8*)(xb + 4352);
                }
                #pragma unroll
                for (int nt = 0; nt < 2; ++nt) {
                    int gn = mh*128 + (wv*2 + nt)*16 + l16;
                    short8 bh = *(const short8*)(wsp + W1H + gn*C_ + ks*32 + quad*8);
                    short8 bl = *(const short8*)(wsp + W1L + gn*C_ + ks*32 + quad*8);
                    #pragma unroll
                    for (int mt = 0; mt < 2; ++mt) { MFMA3(accH[mt][nt], bh, bl, ah[mt], al[mt]); }
                }
            }
            #pragma unroll
            for (int nt = 0; nt < 2; ++nt) {
                int ch0 = (wv*2 + nt)*16 + quad*4;
                f32x4 b14 = *(const f32x4*)(b1 + mh*128 + ch0);
                #pragma unroll
                for (int mt = 0; mt < 2; ++mt) {
                    int tk = mt*16 + l16;
                    u16 hh[4], ll[4];
                    #pragma unroll
                    for (int r = 0; r < 4; ++r) {
                        float v = accH[mt][nt][r] + b14[r];
                        float ge = 0.5f * v * (1.f + erff(v * 0.70710678118654752f));
                        split2(ge, hh[r], ll[r]);
                    }
                    char* hb = pool + HM_H + tk*272 + ch0*2;
                    *(u16x4*)(hb)        = (u16x4){hh[0],hh[1],hh[2],hh[3]};
                    *(u16x4*)(hb + 8704) = (u16x4){ll[0],ll[1],ll[2],ll[3]};
                }
            }
        }
        __syncthreads();
        {
            #pragma unroll
            for (int ks = 0; ks < 4; ++ks) {
                short8 ah[2], al[2];
                #pragma unroll
                for (int mt = 0; mt < 2; ++mt) {
                    const char* hb = pool + HM_H + (mt*16 + l16)*272 + ks*64 + quad*16;
                    ah[mt] = *(const short8*)(hb);
                    al[mt] = *(const short8*)(hb + 8704);
                }
                #pragma unroll
                for (int nt = 0; nt < 2; ++nt) {
                    int n = (wv*2 + nt)*16 + l16;
                    short8 bh = *(const short8*)(wsp + W2H + n*C4_ + mh*128 + ks*32 + quad*8);
                    short8 bl = *(const short8*)(wsp + W2L + n*C4_ + mh*128 + ks*32 + quad*8);
                    #pragma unroll
                    for (int mt = 0; mt < 2; ++mt) { MFMA3(accO[mt][nt], bh, bl, ah[mt], al[mt]); }
                }
            }
        }
        __syncthreads();
    }

    // ---- Epilogue: y = o1 + mlp + b2, strided store ----
    {
        const float* O1 = (const float*)(pool + O1B);
        float* ob = out + (size_t)b * (T_*C_*HW_) + hw;
        #pragma unroll
        for (int mt = 0; mt < 2; ++mt) {
            int tk = mt*16 + l16;
            #pragma unroll
            for (int nt = 0; nt < 2; ++nt) {
                int ch0 = (wv*2 + nt)*16 + quad*4;
                f32x4 o4  = *(const f32x4*)(O1 + tk*132 + ch0);
                f32x4 b24 = *(const f32x4*)(b2 + ch0);
                #pragma unroll
                for (int r = 0; r < 4; ++r) {
                    float y = o4[r] + accO[mt][nt][r] + b24[r];
                    ob[(size_t)(tk*C_ + ch0 + r) * HW_] = y;
                }
            }
        }
    }
}

extern "C" void kernel_launch(void* const* d_in, const int* in_sizes, int n_in,
                              void* d_out, int out_size, void* d_ws, size_t ws_size,
                              hipStream_t stream)
{
    const float* x   = (const float*)d_in[0];
    const float* gui = (const float*)d_in[1];
    const float* Wq  = (const float*)d_in[2];
    const float* bq  = (const float*)d_in[3];
    const float* Wk  = (const float*)d_in[4];
    const float* bk  = (const float*)d_in[5];
    const float* Wv  = (const float*)d_in[6];
    const float* bv  = (const float*)d_in[7];
    const float* g1  = (const float*)d_in[8];
    const float* be1 = (const float*)d_in[9];
    const float* g2  = (const float*)d_in[10];
    const float* be2 = (const float*)d_in[11];
    const float* W1  = (const float*)d_in[12];
    const float* b1  = (const float*)d_in[13];
    const float* W2  = (const float*)d_in[14];
    const float* b2  = (const float*)d_in[15];
    u16* wsp = (u16*)d_ws;

    int use_xt = (ws_size >= WS_NEED_BYTES) ? 1 : 0;

    prep_weights<<<dim3(800), dim3(256), 0, stream>>>(Wq, Wk, Wv, W1, W2, gui, wsp);
    if (use_xt)
        transpose_x<<<dim3(8192), dim3(256), 0, stream>>>(x, wsp);

    (void)hipFuncSetAttribute((const void*)fused_linattn_mfma,
                              hipFuncAttributeMaxDynamicSharedMemorySize,
                              POOLB);
    fused_linattn_mfma<<<dim3(4096), dim3(256), POOLB, stream>>>(
        x, bq, bk, bv, g1, be1, g2, be2, b1, b2, wsp, use_xt, (float*)d_out);
}

// Round 2
// 563.611 us; speedup vs baseline: 1.1294x; 1.0396x over previous
//
#include <hip/hip_runtime.h>
#include <hip/hip_bf16.h>
#include <math.h>

#define T_   32
#define C_   128
#define GD_  64
#define KQK_ 192
#define NH_  4
#define HD_  32
#define C4_  512
#define HW_  1024

typedef unsigned short u16;
typedef __attribute__((ext_vector_type(8))) short short8;
typedef __attribute__((ext_vector_type(4))) short short4v;
typedef __attribute__((ext_vector_type(4))) float f32x4;
typedef __attribute__((ext_vector_type(4))) unsigned short u16x4;

// ---- ws layout ----
// f32 region at byte [0,4096): a[512] (sum W1*g2), cpl[512] (sum W1*be2 + b1)
#define ACF_A 0
#define ACF_C 512
// u16 element offsets (all +2048 vs previous layout to make room for a/cpl)
#define WQH 2048
#define WQL 26624
#define WKH 51200
#define WKL 75776
#define WVH 100352
#define WVL 116736
#define W1H 133120
#define W1L 198656
#define W2H 264192
#define W2L 329728
#define GSH 395264
#define GSL 403456
#define XT  411648           // per-n interleaved: [n][hi 4096 u16 | lo 4096 u16]
#define WS_NEED_BYTES (823296ull + 4096ull*8192ull*2ull)   // 67,932,160

// ---- LDS pool byte offsets (O1 eliminated; X2/HM overlay AX) ----
#define AX_H  0        // [32][200] u16 (x|g hi), stride 400 B   (phases A-O)
#define AX_L  12800    // [32][200] u16 (lo), ends 25600
#define X2A_H 0        // o1 raw split, rows 0-15  [16][136] u16 (overlays AX)
#define X2A_L 4352
#define X2B_H 8704     // rows 16-31
#define X2B_L 13056    // ends 17408
#define HM_H  17408    // [32][136] u16 (overlays AX tail)
#define HM_L  26112    // ends 34816
#define KSUM  34816    // 128 f32
#define ZDEN  35328    // 128 f32 [head][token]
#define STATS 35840    // 128 f32: mu1[32] rs1[32] mu2*rs2[32] rs2[32]
#define LN2P  36352    // 256 f32: m[4 waves][32 t], s[4][32]
#define POOLB 37376    // 4 blocks/CU (163840/4 = 40960)

__device__ __forceinline__ float b2f(u16 u) {
    unsigned int x = ((unsigned int)u) << 16;
    float f; __builtin_memcpy(&f, &x, 4); return f;
}
__device__ __forceinline__ u16 f2b(float f) {
    __hip_bfloat16 h = __float2bfloat16(f);
    u16 u; __builtin_memcpy(&u, &h, 2); return u;
}
__device__ __forceinline__ void split2(float v, u16& h, u16& l) {
    h = f2b(v); l = f2b(v - b2f(h));
}
__device__ __forceinline__ void splitfrag(const f32x4 v, short4v& h, short4v& l) {
    u16 hh[4], ll[4];
    #pragma unroll
    for (int r = 0; r < 4; ++r) { hh[r] = f2b(v[r]); ll[r] = f2b(v[r] - b2f(hh[r])); }
    h = (short4v){(short)hh[0],(short)hh[1],(short)hh[2],(short)hh[3]};
    l = (short4v){(short)ll[0],(short)ll[1],(short)ll[2],(short)ll[3]};
}

__device__ __forceinline__ f32x4 mfma16(short4v a, short4v b, f32x4 c) {
#if __has_builtin(__builtin_amdgcn_mfma_f32_16x16x16bf16_1k)
    return __builtin_amdgcn_mfma_f32_16x16x16bf16_1k(a, b, c, 0, 0, 0);
#else
    asm("v_mfma_f32_16x16x16_bf16 %0, %1, %2, %0" : "+v"(c) : "v"(a), "v"(b));
    return c;
#endif
}

#define MFMA3(acc, ah, al, bh, bl)                                          \
    acc = __builtin_amdgcn_mfma_f32_16x16x32_bf16(ah, bh, acc, 0, 0, 0);    \
    acc = __builtin_amdgcn_mfma_f32_16x16x32_bf16(ah, bl, acc, 0, 0, 0);    \
    acc = __builtin_amdgcn_mfma_f32_16x16x32_bf16(al, bh, acc, 0, 0, 0);

#define MFMA3_16(acc, ah, al, bh, bl)                                       \
    acc = mfma16(ah, bh, acc);                                              \
    acc = mfma16(ah, bl, acc);                                              \
    acc = mfma16(al, bh, acc);

// ---- prep: split weights (transposed [n][K], W1 pre-scaled by g2) + guidance
//      + a[n]=sum_k W1*g2, cpl[n]=sum_k W1*be2 + b1 ----
__global__ void prep_weights(const float* __restrict__ Wq, const float* __restrict__ Wk,
                             const float* __restrict__ Wv, const float* __restrict__ W1,
                             const float* __restrict__ W2, const float* __restrict__ gui,
                             const float* __restrict__ g2, const float* __restrict__ be2,
                             const float* __restrict__ b1,
                             u16* __restrict__ wsp)
{
    int e = blockIdx.x * 256 + threadIdx.x;
    if (e >= 204800) {                       // a/cpl tail: 512 elems
        int n = e - 204800;
        if (n >= 512) return;
        float a = 0.f, c = 0.f;
        for (int k = 0; k < 128; ++k) {
            float w = W1[k*512 + n];
            a = fmaf(w, g2[k], a);
            c = fmaf(w, be2[k], c);
        }
        float* acf = (float*)wsp;
        acf[ACF_A + n] = a;
        acf[ACF_C + n] = c + b1[n];
        return;
    }
    if (e >= 196608) {                       // guidance: 8192 elems
        int idx = e - 196608;
        float v = gui[idx];
        u16 hb = f2b(v);
        wsp[GSH + idx] = hb;
        wsp[GSL + idx] = f2b(v - b2f(hb));
        return;
    }
    const float* src; int e2, k, n, K; int oh, ol; int isW1 = 0;
    if (e < 24576)       { src = Wq; e2 = e;          k = e2 >> 7; n = e2 & 127; K = KQK_; oh = WQH; ol = WQL; }
    else if (e < 49152)  { src = Wk; e2 = e - 24576;  k = e2 >> 7; n = e2 & 127; K = KQK_; oh = WKH; ol = WKL; }
    else if (e < 65536)  { src = Wv; e2 = e - 49152;  k = e2 >> 7; n = e2 & 127; K = C_;   oh = WVH; ol = WVL; }
    else if (e < 131072) { src = W1; e2 = e - 65536;  k = e2 >> 9; n = e2 & 511; K = C_;   oh = W1H; ol = W1L; isW1 = 1; }
    else                 { src = W2; e2 = e - 131072; k = e2 >> 7; n = e2 & 127; K = C4_;  oh = W2H; ol = W2L; }
    float w = src[e2];
    if (isW1) w *= g2[k];
    u16 hb = f2b(w);
    wsp[oh + n * K + k] = hb;
    wsp[ol + n * K + k] = f2b(w - b2f(hb));
}

// ---- transpose x (B,T,C,H,W) -> xT[n][t][c] split bf16 planes ----
__global__ __launch_bounds__(256) void transpose_x(const float* __restrict__ x, u16* __restrict__ wsp)
{
    __shared__ float tile[32][65];
    int bid = blockIdx.x;
    int hq = bid & 15, cq = (bid >> 4) & 3, t = (bid >> 6) & 31, b = bid >> 11;
    int c0 = cq * 32, hw0 = hq * 64;
    int tid = threadIdx.x;
    {
        int i = tid >> 3, j8 = (tid & 7) * 8;
        const float* src = x + ((size_t)((b*32 + t)*128 + c0 + i))*1024 + hw0 + j8;
        float4 v0 = *reinterpret_cast<const float4*>(src);
        float4 v1 = *reinterpret_cast<const float4*>(src + 4);
        tile[i][j8+0]=v0.x; tile[i][j8+1]=v0.y; tile[i][j8+2]=v0.z; tile[i][j8+3]=v0.w;
        tile[i][j8+4]=v1.x; tile[i][j8+5]=v1.y; tile[i][j8+6]=v1.z; tile[i][j8+7]=v1.w;
    }
    __syncthreads();
    {
        int jj = tid >> 2, c8 = (tid & 3) * 8;
        int n = b*1024 + hw0 + jj;
        u16 hh[8], ll[8];
        #pragma unroll
        for (int ii = 0; ii < 8; ++ii) {
            float v = tile[c8 + ii][jj];
            u16 hb = f2b(v);
            hh[ii] = hb; ll[ii] = f2b(v - b2f(hb));
        }
        u16* dh = wsp + XT + (size_t)n*8192 + t*128 + c0 + c8;
        u16* dl = dh + 4096;
        *reinterpret_cast<ushort4*>(dh)     = make_ushort4(hh[0],hh[1],hh[2],hh[3]);
        *reinterpret_cast<ushort4*>(dh + 4) = make_ushort4(hh[4],hh[5],hh[6],hh[7]);
        *reinterpret_cast<ushort4*>(dl)     = make_ushort4(ll[0],ll[1],ll[2],ll[3]);
        *reinterpret_cast<ushort4*>(dl + 4) = make_ushort4(ll[4],ll[5],ll[6],ll[7]);
    }
}

__global__ __launch_bounds__(256, 4) void fused_linattn_mfma(
    const float* __restrict__ x,
    const float* __restrict__ bq, const float* __restrict__ bk, const float* __restrict__ bv,
    const float* __restrict__ g1, const float* __restrict__ be1,
    const float* __restrict__ b2,
    const u16* __restrict__ wsp, int use_xt,
    float* __restrict__ out)
{
    extern __shared__ __align__(16) char pool[];
    float* ksum  = (float*)(pool + KSUM);
    float* zf    = (float*)(pool + ZDEN);
    float* stats = (float*)(pool + STATS);
    float* ln2p  = (float*)(pool + LN2P);
    const float* acf = (const float*)wsp;

    const int bi  = blockIdx.x;
    const int n_  = ((bi & 7) << 9) | (bi >> 3);
    const int b   = n_ >> 10;
    const int hw  = n_ & 1023;
    const int tid = threadIdx.x;
    const int lane = tid & 63, wv = tid >> 6;
    const int l16  = lane & 15, quad = lane >> 4;

    // ---- Phase A: stage x|g split planes into AX ----
    if (use_xt) {
        const u16* xtb = wsp + XT + (size_t)n_ * 8192;
        #pragma unroll
        for (int i = 0; i < 2; ++i) {
            int off = (tid + i*256) * 8;
            int t = off >> 7, c = off & 127;
            short8 vh = *reinterpret_cast<const short8*>(xtb + off);
            short8 vl = *reinterpret_cast<const short8*>(xtb + 4096 + off);
            *reinterpret_cast<short8*>(pool + AX_H + t*400 + c*2) = vh;
            *reinterpret_cast<short8*>(pool + AX_L + t*400 + c*2) = vl;
        }
    } else {
        const float* xb = x + (size_t)b * (T_*C_*HW_) + hw;
        #pragma unroll
        for (int i = 0; i < 16; ++i) {
            int idx = tid + i*256;
            float v = xb[(size_t)idx * HW_];
            int t = idx >> 7, c = idx & 127;
            u16 hb = f2b(v);
            *(u16*)(pool + AX_H + t*400 + c*2) = hb;
            *(u16*)(pool + AX_L + t*400 + c*2) = f2b(v - b2f(hb));
        }
    }
    {
        const u16* gh = wsp + GSH + b*2048 + tid*8;
        const u16* gl = wsp + GSL + b*2048 + tid*8;
        int off = tid * 8;
        int t = off >> 6, jg = off & 63;
        short8 vh = *reinterpret_cast<const short8*>(gh);
        short8 vl = *reinterpret_cast<const short8*>(gl);
        *reinterpret_cast<short8*>(pool + AX_H + t*400 + 256 + jg*2) = vh;
        *reinterpret_cast<short8*>(pool + AX_L + t*400 + 256 + jg*2) = vl;
    }
    __syncthreads();

    // ---- Phase B: fused QKV projections (shared AX frags), all results -> regs ----
    // wave wv owns channels [wv*32, wv*32+32) == head wv.
    // 16x16x16 frag layouts chain directly from 16x16x32 acc layouts (no shuffles).
    short4v qfh[2][2], qfl[2][2];   // [tt][dt]: Q' A-frag: row=token(l16), k=d(quad*4+i)
    short4v kfh[2][2], kfl[2][2];   // [tt][dt]: K' A-frag: row=d(l16), k=token(quad*4+i)
    short4v vfh[2][2], vfl[2][2];   // [tt][vt]: V  B-frag: col=v(l16), k=token(quad*4+i)
    {
        f32x4 aq[2][2], ak[2][2], av[2][2];
        #pragma unroll
        for (int mt = 0; mt < 2; ++mt)
            #pragma unroll
            for (int nt = 0; nt < 2; ++nt) {
                aq[mt][nt] = (f32x4){0.f,0.f,0.f,0.f};
                ak[mt][nt] = (f32x4){0.f,0.f,0.f,0.f};
                av[mt][nt] = (f32x4){0.f,0.f,0.f,0.f};
            }
        #pragma unroll
        for (int ks = 0; ks < 6; ++ks) {
            short8 ah[2], al[2];
            #pragma unroll
            for (int mt = 0; mt < 2; ++mt) {
                ah[mt] = *(const short8*)(pool + AX_H + (mt*16 + l16)*400 + ks*64 + quad*16);
                al[mt] = *(const short8*)(pool + AX_L + (mt*16 + l16)*400 + ks*64 + quad*16);
            }
            #pragma unroll
            for (int nt = 0; nt < 2; ++nt) {
                int n = (wv*2 + nt)*16 + l16;
                {   // Q swapped: acc = [channel][token]
                    short8 bh = *(const short8*)(wsp + WQH + n*KQK_ + ks*32 + quad*8);
                    short8 bl = *(const short8*)(wsp + WQL + n*KQK_ + ks*32 + quad*8);
                    #pragma unroll
                    for (int mt = 0; mt < 2; ++mt) { MFMA3(aq[mt][nt], bh, bl, ah[mt], al[mt]); }
                }
                {   // K normal: acc = [token][channel]
                    short8 bh = *(const short8*)(wsp + WKH + n*KQK_ + ks*32 + quad*8);
                    short8 bl = *(const short8*)(wsp + WKL + n*KQK_ + ks*32 + quad*8);
                    #pragma unroll
                    for (int mt = 0; mt < 2; ++mt) { MFMA3(ak[mt][nt], ah[mt], al[mt], bh, bl); }
                }
                if (ks < 4) {   // V normal
                    short8 bh = *(const short8*)(wsp + WVH + n*C_ + ks*32 + quad*8);
                    short8 bl = *(const short8*)(wsp + WVL + n*C_ + ks*32 + quad*8);
                    #pragma unroll
                    for (int mt = 0; mt < 2; ++mt) { MFMA3(av[mt][nt], ah[mt], al[mt], bh, bl); }
                }
            }
        }
        // Q epilogue: elu+1, split -> qf
        #pragma unroll
        for (int ct = 0; ct < 2; ++ct) {
            f32x4 bq4 = *(const f32x4*)(bq + wv*32 + ct*16 + quad*4);
            #pragma unroll
            for (int tt = 0; tt < 2; ++tt) {
                f32x4 qp;
                #pragma unroll
                for (int r = 0; r < 4; ++r) {
                    float q = aq[tt][ct][r] + bq4[r];
                    qp[r] = (q > 0.f) ? q + 1.f : __expf(q);
                }
                splitfrag(qp, qfh[tt][ct], qfl[tt][ct]);
            }
        }
        // K epilogue: elu+1, split -> kf; ksum
        float sk0 = 0.f, sk1 = 0.f;
        #pragma unroll
        for (int nt = 0; nt < 2; ++nt) {
            float bias = bk[wv*32 + nt*16 + l16];
            #pragma unroll
            for (int mt = 0; mt < 2; ++mt) {
                f32x4 kp;
                #pragma unroll
                for (int r = 0; r < 4; ++r) {
                    float k = ak[mt][nt][r] + bias;
                    float v = (k > 0.f) ? k + 1.f : __expf(k);
                    kp[r] = v;
                    if (nt == 0) sk0 += v; else sk1 += v;
                }
                splitfrag(kp, kfh[mt][nt], kfl[mt][nt]);
            }
        }
        sk0 += __shfl_xor(sk0, 16); sk0 += __shfl_xor(sk0, 32);
        sk1 += __shfl_xor(sk1, 16); sk1 += __shfl_xor(sk1, 32);
        if (quad == 0) { ksum[wv*32 + l16] = sk0; ksum[wv*32 + 16 + l16] = sk1; }
        // V epilogue: split -> vf
        #pragma unroll
        for (int nt = 0; nt < 2; ++nt) {
            float bias = bv[wv*32 + nt*16 + l16];
            #pragma unroll
            for (int mt = 0; mt < 2; ++mt) {
                f32x4 vp;
                #pragma unroll
                for (int r = 0; r < 4; ++r) vp[r] = av[mt][nt][r] + bias;
                splitfrag(vp, vfh[mt][nt], vfl[mt][nt]);
            }
        }
    }

    // ---- zden (wave-local: ksum of own head) ----
    {
        f32x4 ka0 = *(const f32x4*)(ksum + wv*32 + quad*4);
        f32x4 ka1 = *(const f32x4*)(ksum + wv*32 + 16 + quad*4);
        float p0 = 0.f, p1 = 0.f;
        #pragma unroll
        for (int i = 0; i < 4; ++i) {
            p0 = fmaf(b2f((u16)(short)qfh[0][0][i]) + b2f((u16)(short)qfl[0][0][i]), ka0[i], p0);
            p0 = fmaf(b2f((u16)(short)qfh[0][1][i]) + b2f((u16)(short)qfl[0][1][i]), ka1[i], p0);
            p1 = fmaf(b2f((u16)(short)qfh[1][0][i]) + b2f((u16)(short)qfl[1][0][i]), ka0[i], p1);
            p1 = fmaf(b2f((u16)(short)qfh[1][1][i]) + b2f((u16)(short)qfl[1][1][i]), ka1[i], p1);
        }
        p0 += __shfl_xor(p0, 16); p0 += __shfl_xor(p0, 32);
        p1 += __shfl_xor(p1, 16); p1 += __shfl_xor(p1, 32);
        if (quad == 0) {
            zf[wv*32 + l16]      = 1.f / (p0 + 1e-6f);
            zf[wv*32 + 16 + l16] = 1.f / (p1 + 1e-6f);
        }
    }

    // ---- KV in registers: kv[dt][vt] += kf[tt][dt] x vf[tt][vt] (16x16x16) ----
    short4v kvfh[2][2], kvfl[2][2];   // [dt][vt]: B-frag: col=v(l16), k=d(quad*4+i)
    #pragma unroll
    for (int dt = 0; dt < 2; ++dt)
        #pragma unroll
        for (int vt = 0; vt < 2; ++vt) {
            f32x4 kv = (f32x4){0.f,0.f,0.f,0.f};
            #pragma unroll
            for (int tt = 0; tt < 2; ++tt) {
                MFMA3_16(kv, kfh[tt][dt], kfl[tt][dt], vfh[tt][vt], vfl[tt][vt]);
            }
            splitfrag(kv, kvfh[dt][vt], kvfl[dt][vt]);
        }

    // ---- ln1 stats (cross-wave, 8 threads/row) ----
    {
        int t = tid >> 3, j = tid & 7;
        const char* rp = pool + AX_H + t*400 + j*32;
        short8 h0 = *(const short8*)(rp);
        short8 h1 = *(const short8*)(rp + 16);
        short8 l0 = *(const short8*)(rp + (AX_L - AX_H));
        short8 l1 = *(const short8*)(rp + (AX_L - AX_H) + 16);
        float m = 0.f, s = 0.f;
        #pragma unroll
        for (int i = 0; i < 8; ++i) {
            float v = b2f((u16)h0[i]) + b2f((u16)l0[i]);
            m += v; s = fmaf(v, v, s);
            v = b2f((u16)h1[i]) + b2f((u16)l1[i]);
            m += v; s = fmaf(v, v, s);
        }
        m += __shfl_xor(m, 1); s += __shfl_xor(s, 1);
        m += __shfl_xor(m, 2); s += __shfl_xor(s, 2);
        m += __shfl_xor(m, 4); s += __shfl_xor(s, 4);
        if (j == 0) {
            float mu = m * (1.f/C_);
            stats[t]      = mu;
            stats[32 + t] = rsqrtf(s * (1.f/C_) - mu*mu + 1e-5f);
        }
    }
    __syncthreads();

    // ---- Phase O: o = Q' x KV (16x16x16) + zden scale + ln1 residual -> o1v regs ----
    f32x4 o1v[2][2];   // [tt][vt]: token = tt*16+quad*4+r, ch = wv*32+vt*16+l16
    #pragma unroll
    for (int tt = 0; tt < 2; ++tt) {
        f32x4 zd4 = *(const f32x4*)(zf + wv*32 + tt*16 + quad*4);
        f32x4 mu4 = *(const f32x4*)(stats + tt*16 + quad*4);
        f32x4 rs4 = *(const f32x4*)(stats + 32 + tt*16 + quad*4);
        #pragma unroll
        for (int vt = 0; vt < 2; ++vt) {
            f32x4 oa = (f32x4){0.f,0.f,0.f,0.f};
            #pragma unroll
            for (int dt = 0; dt < 2; ++dt) {
                MFMA3_16(oa, qfh[tt][dt], qfl[tt][dt], kvfh[dt][vt], kvfl[dt][vt]);
            }
            int ch = wv*32 + vt*16 + l16;
            float g1c = g1[ch], be1c = be1[ch];
            #pragma unroll
            for (int r = 0; r < 4; ++r) {
                int t = tt*16 + quad*4 + r;
                float xv = b2f(*(const u16*)(pool + AX_H + t*400 + ch*2))
                         + b2f(*(const u16*)(pool + AX_L + t*400 + ch*2));
                o1v[tt][vt][r] = oa[r]*zd4[r] + (xv - mu4[r])*rs4[r]*g1c + be1c;
            }
        }
    }
    // ln2 partials: sum over this wave's 32 channels per token
    {
        float pm[2][4], ps[2][4];
        #pragma unroll
        for (int tt = 0; tt < 2; ++tt)
            #pragma unroll
            for (int r = 0; r < 4; ++r) {
                float v0 = o1v[tt][0][r], v1 = o1v[tt][1][r];
                float m = v0 + v1;
                float s = v0*v0 + v1*v1;
                m += __shfl_xor(m, 1); s += __shfl_xor(s, 1);
                m += __shfl_xor(m, 2); s += __shfl_xor(s, 2);
                m += __shfl_xor(m, 4); s += __shfl_xor(s, 4);
                m += __shfl_xor(m, 8); s += __shfl_xor(s, 8);
                pm[tt][r] = m; ps[tt][r] = s;
            }
        if (l16 == 0) {
            #pragma unroll
            for (int tt = 0; tt < 2; ++tt)
                #pragma unroll
                for (int r = 0; r < 4; ++r) {
                    int t = tt*16 + quad*4 + r;
                    ln2p[wv*32 + t]       = pm[tt][r];
                    ln2p[128 + wv*32 + t] = ps[tt][r];
                }
        }
    }
    __syncthreads();   // AX dead; LN2P visible

    // ---- X2 = raw o1 split planes (normalization folded into W1g/a/cpl) ----
    #pragma unroll
    for (int tt = 0; tt < 2; ++tt) {
        char* xb = pool + (tt ? X2B_H : X2A_H);
        #pragma unroll
        for (int vt = 0; vt < 2; ++vt) {
            int ch = wv*32 + vt*16 + l16;
            #pragma unroll
            for (int r = 0; r < 4; ++r) {
                u16 hb, lb; split2(o1v[tt][vt][r], hb, lb);
                int off = (quad*4 + r)*272 + ch*2;
                *(u16*)(xb + off)        = hb;
                *(u16*)(xb + 4352 + off) = lb;
            }
        }
    }
    if (tid < 32) {    // ln2 stats finalize
        int t = tid;
        float m = 0.f, s = 0.f;
        #pragma unroll
        for (int w = 0; w < 4; ++w) { m += ln2p[w*32 + t]; s += ln2p[128 + w*32 + t]; }
        float mu = m * (1.f/C_);
        float rs = rsqrtf(s * (1.f/C_) - mu*mu + 1e-5f);
        stats[64 + t] = mu * rs;
        stats[96 + t] = rs;
    }
    __syncthreads();

    // ---- Phases F/G: MLP, 4 chunks of 128; F swapped (A=W1g), G normal (A=hm) ----
    f32x4 accO[2][2];   // [mt][nt]: token = mt*16+quad*4+r, out_ch = (wv*2+nt)*16+l16
    #pragma unroll
    for (int mt = 0; mt < 2; ++mt)
        #pragma unroll
        for (int nt = 0; nt < 2; ++nt) accO[mt][nt] = (f32x4){0.f,0.f,0.f,0.f};

    #pragma unroll 1
    for (int mh = 0; mh < 4; ++mh) {
        {
            f32x4 accH[2][2];
            #pragma unroll
            for (int mt = 0; mt < 2; ++mt)
                #pragma unroll
                for (int nt = 0; nt < 2; ++nt) accH[mt][nt] = (f32x4){0.f,0.f,0.f,0.f};
            #pragma unroll
            for (int ks = 0; ks < 4; ++ks) {
                short8 ah[2], al[2];
                #pragma unroll
                for (int mt = 0; mt < 2; ++mt) {
                    const char* xb = pool + (mt ? X2B_H : X2A_H) + l16*272 + ks*64 + quad*16;
                    ah[mt] = *(const short8*)(xb);
                    al[mt] = *(const short8*)(xb + 4352);
                }
                #pragma unroll
                for (int nt = 0; nt < 2; ++nt) {
                    int gn = mh*128 + (wv*2 + nt)*16 + l16;
                    short8 bh = *(const short8*)(wsp + W1H + gn*C_ + ks*32 + quad*8);
                    short8 bl = *(const short8*)(wsp + W1L + gn*C_ + ks*32 + quad*8);
                    #pragma unroll
                    for (int mt = 0; mt < 2; ++mt) { MFMA3(accH[mt][nt], bh, bl, ah[mt], al[mt]); }
                }
            }
            #pragma unroll
            for (int nt = 0; nt < 2; ++nt) {
                int base = mh*128 + (wv*2 + nt)*16 + quad*4;
                f32x4 a4 = *(const f32x4*)(acf + ACF_A + base);
                f32x4 c4 = *(const f32x4*)(acf + ACF_C + base);
                int ch0 = (wv*2 + nt)*16 + quad*4;
                #pragma unroll
                for (int mt = 0; mt < 2; ++mt) {
                    int tk = mt*16 + l16;
                    float mrs = stats[64 + tk], rsv = stats[96 + tk];
                    u16 hh[4], ll[4];
                    #pragma unroll
                    for (int r = 0; r < 4; ++r) {
                        float v = accH[mt][nt][r]*rsv - mrs*a4[r] + c4[r];
                        float ge = 0.5f * v * (1.f + erff(v * 0.70710678118654752f));
                        split2(ge, hh[r], ll[r]);
                    }
                    char* hb = pool + HM_H + tk*272 + ch0*2;
                    *(u16x4*)(hb)        = (u16x4){hh[0],hh[1],hh[2],hh[3]};
                    *(u16x4*)(hb + 8704) = (u16x4){ll[0],ll[1],ll[2],ll[3]};
                }
            }
        }
        __syncthreads();
        {
            #pragma unroll
            for (int ks = 0; ks < 4; ++ks) {
                short8 ah[2], al[2];
                #pragma unroll
                for (int mt = 0; mt < 2; ++mt) {
                    const char* hb = pool + HM_H + (mt*16 + l16)*272 + ks*64 + quad*16;
                    ah[mt] = *(const short8*)(hb);
                    al[mt] = *(const short8*)(hb + 8704);
                }
                #pragma unroll
                for (int nt = 0; nt < 2; ++nt) {
                    int n = (wv*2 + nt)*16 + l16;
                    short8 bh = *(const short8*)(wsp + W2H + n*C4_ + mh*128 + ks*32 + quad*8);
                    short8 bl = *(const short8*)(wsp + W2L + n*C4_ + mh*128 + ks*32 + quad*8);
                    #pragma unroll
                    for (int mt = 0; mt < 2; ++mt) { MFMA3(accO[mt][nt], ah[mt], al[mt], bh, bl); }
                }
            }
        }
        if (mh < 3) __syncthreads();
    }

    // ---- Epilogue: y = o1v + mlp + b2 (aligned register layouts), strided store ----
    {
        float* ob = out + (size_t)b * (T_*C_*HW_) + hw;
        #pragma unroll
        for (int mt = 0; mt < 2; ++mt) {
            #pragma unroll
            for (int nt = 0; nt < 2; ++nt) {
                int ch = wv*32 + nt*16 + l16;
                float b2c = b2[ch];
                #pragma unroll
                for (int r = 0; r < 4; ++r) {
                    int t = mt*16 + quad*4 + r;
                    float y = o1v[mt][nt][r] + accO[mt][nt][r] + b2c;
                    ob[(size_t)(t*C_ + ch) * HW_] = y;
                }
            }
        }
    }
}

extern "C" void kernel_launch(void* const* d_in, const int* in_sizes, int n_in,
                              void* d_out, int out_size, void* d_ws, size_t ws_size,
                              hipStream_t stream)
{
    const float* x   = (const float*)d_in[0];
    const float* gui = (const float*)d_in[1];
    const float* Wq  = (const float*)d_in[2];
    const float* bq  = (const float*)d_in[3];
    const float* Wk  = (const float*)d_in[4];
    const float* bk  = (const float*)d_in[5];
    const float* Wv  = (const float*)d_in[6];
    const float* bv  = (const float*)d_in[7];
    const float* g1  = (const float*)d_in[8];
    const float* be1 = (const float*)d_in[9];
    const float* g2  = (const float*)d_in[10];
    const float* be2 = (const float*)d_in[11];
    const float* W1  = (const float*)d_in[12];
    const float* b1  = (const float*)d_in[13];
    const float* W2  = (const float*)d_in[14];
    const float* b2  = (const float*)d_in[15];
    u16* wsp = (u16*)d_ws;

    int use_xt = (ws_size >= WS_NEED_BYTES) ? 1 : 0;

    prep_weights<<<dim3(802), dim3(256), 0, stream>>>(Wq, Wk, Wv, W1, W2, gui, g2, be2, b1, wsp);
    if (use_xt)
        transpose_x<<<dim3(8192), dim3(256), 0, stream>>>(x, wsp);

    (void)hipFuncSetAttribute((const void*)fused_linattn_mfma,
                              hipFuncAttributeMaxDynamicSharedMemorySize,
                              POOLB);
    fused_linattn_mfma<<<dim3(4096), dim3(256), POOLB, stream>>>(
        x, bq, bk, bv, g1, be1, b2, wsp, use_xt, (float*)d_out);
}